// Round 1
// 337.816 us; speedup vs baseline: 1.1599x; 1.1599x over previous
//
#include <hip/hip_runtime.h>
#include <hip/hip_fp16.h>

#define F_IN 256
#define HEADS 8
#define F_HEAD 32
#define HF 256            // HEADS * F_HEAD
#define NEG_SLOPE 0.2f

typedef float    floatx4 __attribute__((ext_vector_type(4)));
typedef short    shortx8 __attribute__((ext_vector_type(8)));
typedef _Float16 halfx4  __attribute__((ext_vector_type(4)));
typedef _Float16 halfx8  __attribute__((ext_vector_type(8)));

__device__ __forceinline__ float bf2f(unsigned short u) {
    return __uint_as_float(((unsigned int)u) << 16);
}
__device__ __forceinline__ unsigned short f2bf(float f) {
    unsigned int b = __float_as_uint(f);
    b += 0x7FFFu + ((b >> 16) & 1u);   // RNE; exact for on-grid values
    return (unsigned short)(b >> 16);
}

// flags[0] bit0: edge_index int32 (else int64)
// flags[0] bit1: float tensors fp32-stored (incl. bf16-grid fp32) else packed bf16
// flags[0] bits3-4: which 256-elem candidate is bias (all-zero)
// flags[1]: nonzero count of sampled even uint16 halves of x; flags[2]: large-seen
__device__ __forceinline__ int edge_at(const void* ei, int is32, long long idx) {
    if (is32) return ((const int*)ei)[idx];
    return (int)((const long long*)ei)[idx];
}
__device__ __forceinline__ float fload(const void* p, int isf32, int idx) {
    if (isf32) return ((const float*)p)[idx];
    return bf2f(((const unsigned short*)p)[idx]);
}

// ---------------------------------------------------------------------------
// Fused detection: blocks 0-127 probe edge_index width; blocks 128-255 probe
// float encoding on x (three-way: plain fp32 / bf16-grid fp32 / packed bf16).
__global__ void detect_all(const unsigned int* eiw, int E,
                           const unsigned short* xu, int xnels, int* flags) {
    int b = blockIdx.x;
    if (b < 128) {
        int i = b * 256 + threadIdx.x;
        int stride = 128 * 256;
        unsigned int acc = 0;
        for (; i < E; i += stride) acc |= eiw[2 * i + 1];
        if (__any(acc != 0)) {
            if ((threadIdx.x & 63) == 0) atomicOr(&flags[0], 1);
        }
    } else {
        int cap = xnels < (1 << 21) ? xnels : (1 << 21);
        int i = (b - 128) * 256 + threadIdx.x;
        int stride = 128 * 256;
        int large = 0, nz = 0;
        for (int j = 2 * i; j < cap; j += 2 * stride) {
            unsigned short v = xu[j];
            large |= ((v & 0x7FFF) >= 0x4700);
            nz += (v != 0);
        }
#pragma unroll
        for (int off = 32; off; off >>= 1) nz += __shfl_down(nz, off, 64);
        if ((threadIdx.x & 63) == 0 && nz) atomicAdd(&flags[1], nz);
        if (__any(large)) {
            if ((threadIdx.x & 63) == 0) atomicOr(&flags[2], 1);
        }
    }
}

// One block: finalize float flag + find bias (the all-zero 256-elem candidate).
__global__ void finalize_misc(const unsigned int* c0, const unsigned int* c1,
                              const unsigned int* c2, int* flags, int tot) {
    __shared__ int nzf[3];
    int tid = threadIdx.x;
    if (tid < 3) nzf[tid] = 0;
    __syncthreads();
    if (tid < 192) {
        int j = tid >> 6, lane = tid & 63;
        const unsigned int* c = (j == 0) ? c0 : (j == 1) ? c1 : c2;
        if ((c[lane] | c[lane + 64]) != 0) nzf[j] = 1;  // benign race
    }
    __syncthreads();
    if (tid == 0) {
        int bi = (nzf[0] == 0) ? 0 : (nzf[1] == 0) ? 1 : 2;
        int add = bi << 3;
        if (flags[2] != 0 || flags[1] * 2 < tot) add |= 2;
        atomicOr(&flags[0], add);
    }
}

__device__ __forceinline__ void resolve3(const void* c0, const void* c1,
        const void* c2, int fl, const void** as, const void** ad, const void** bs) {
    int bi = (fl >> 3) & 3;
    const void* c[3] = {c0, c1, c2};
    int i0 = (bi == 0) ? 1 : 0;
    int i1 = (bi == 2) ? 1 : 2;
    *as = c[i0];
    *ad = c[i1];
    *bs = c[bi];
}

// ---------------------------------------------------------------------------
// Wt in MFMA-FRAGMENT order: Wt[((ct*8+ks)*64 + lane)*8 + j] = bf16(W[k][n])
// with n = ct*16 + (lane&15), k = ks*32 + (lane>>4)*8 + j.
// This makes every gemm_h B-load a fully coalesced 1 KB wave read (the old
// row-major Wt gave 16 B/lane at 512-B stride = 16 scattered L2 requests
// per load instruction).
__global__ void transpose_w(const void* W, unsigned short* Wt, const int* flags) {
    int isf32 = flags[0] & 2;
    int t = blockIdx.x * 256 + threadIdx.x;          // 0..65535
    int j    = t & 7;
    int lane = (t >> 3) & 63;
    int ks   = (t >> 9) & 7;
    int ct   = (t >> 12) & 15;
    int n = ct * 16 + (lane & 15);
    int k = ks * 32 + (lane >> 4) * 8 + j;
    Wt[t] = isf32 ? f2bf(((const float*)W)[k * 256 + n])
                  : ((const unsigned short*)W)[k * 256 + n];
}

// ---------------------------------------------------------------------------
// h[N][256] fp16 = x @ W. One wave per 16-row strip; A loaded once (32 VGPRs),
// 16 col-tiles stream B from L2 in fragment order (coalesced, address-shared
// across all co-resident waves). C/D layout proven on-silicon (r8/r9).
__global__ __launch_bounds__(256) void gemm_h(const void* x, const short* Wt,
                                              _Float16* h, const int* flags,
                                              int nRows) {
    int xf32 = flags[0] & 2;
    int wid  = (blockIdx.x * blockDim.x + threadIdx.x) >> 6;   // row-strip id
    int lane = threadIdx.x & 63;
    int rowTiles = nRows >> 4;
    if (wid >= rowTiles) return;
    int quad = lane >> 4, m = lane & 15;

    shortx8 a[8];
    size_t arow = (size_t)(wid * 16 + m) * 256 + quad * 8;
    if (xf32) {
        const floatx4* apf = (const floatx4*)((const float*)x + arow);
#pragma unroll
        for (int ks = 0; ks < 8; ++ks) {
            floatx4 f0 = apf[ks * 8], f1 = apf[ks * 8 + 1];
            unsigned int* au = (unsigned int*)&a[ks];
            au[0] = __builtin_amdgcn_perm(__float_as_uint(f0[1]), __float_as_uint(f0[0]), 0x07060302u);
            au[1] = __builtin_amdgcn_perm(__float_as_uint(f0[3]), __float_as_uint(f0[2]), 0x07060302u);
            au[2] = __builtin_amdgcn_perm(__float_as_uint(f1[1]), __float_as_uint(f1[0]), 0x07060302u);
            au[3] = __builtin_amdgcn_perm(__float_as_uint(f1[3]), __float_as_uint(f1[2]), 0x07060302u);
        }
    } else {
        const shortx8* ap = (const shortx8*)((const unsigned short*)x + arow);
#pragma unroll
        for (int ks = 0; ks < 8; ++ks) a[ks] = ap[ks * 4];
    }

    const shortx8* bq = (const shortx8*)Wt;   // index unit: 8 shorts
#pragma unroll 4
    for (int ct = 0; ct < 16; ++ct) {
        const shortx8* bp = bq + (size_t)(ct * 8) * 64 + lane;
        floatx4 acc = {0.f, 0.f, 0.f, 0.f};
#pragma unroll
        for (int ks = 0; ks < 8; ++ks) {
            shortx8 b = bp[(size_t)ks * 64];
            acc = __builtin_amdgcn_mfma_f32_16x16x32_bf16(a[ks], b, acc, 0, 0, 0);
        }
        _Float16* hp = h + (size_t)(wid * 16 + quad * 4) * 256 + ct * 16 + m;
#pragma unroll
        for (int r = 0; r < 4; ++r) hp[(size_t)r * 256] = (_Float16)acc[r];
    }
}

// ---------------------------------------------------------------------------
__global__ __launch_bounds__(256) void att_coef(const _Float16* h,
        const void* c0, const void* c1, const void* c2,
        _Float16* asrc, _Float16* adst, const int* flags, int n) {
    __shared__ float s_src[HF], s_dst[HF];
    int fl = flags[0];
    int isf32 = fl & 2;
    const void *att_src, *att_dst, *bs;
    resolve3(c0, c1, c2, fl, &att_src, &att_dst, &bs);
    int tid = threadIdx.x;
    s_src[tid] = fload(att_src, isf32, tid);
    s_dst[tid] = fload(att_dst, isf32, tid);
    __syncthreads();
    int t = blockIdx.x * 256 + tid;
    if (t >= n * HEADS) return;
    int node = t >> 3, head = t & 7;
    const halfx4* hp = (const halfx4*)(h + (size_t)node * HF + head * F_HEAD);
    float ss = 0.f, sd = 0.f;
#pragma unroll
    for (int i = 0; i < 8; ++i) {
        halfx4 v = hp[i];
        int b = head * 32 + i * 4;
#pragma unroll
        for (int j = 0; j < 4; ++j) {
            float f = (float)v[j];
            ss += f * s_src[b + j];
            sd += f * s_dst[b + j];
        }
    }
    asrc[t] = (_Float16)ss;
    adst[t] = (_Float16)sd;
}

// ---------------------------------------------------------------------------
__global__ void hist_kernel(const void* ei, const int* flags, int E, int* counts, int n) {
    int e = blockIdx.x * 256 + threadIdx.x;
    if (e >= E) return;
    int d = edge_at(ei, flags[0] & 1, (long long)E + e);
    if ((unsigned)d >= (unsigned)n) return;
    atomicAdd(&counts[d], 1);
}

__global__ void scan_blocks(const int* counts, int* row, int* bsum, int n) {
    __shared__ int s[256];
    int tid = threadIdx.x;
    int g = blockIdx.x * 256 + tid;
    int v = (g < n) ? counts[g] : 0;
    s[tid] = v;
    __syncthreads();
    for (int o = 1; o < 256; o <<= 1) {
        int t = (tid >= o) ? s[tid - o] : 0;
        __syncthreads();
        s[tid] += t;
        __syncthreads();
    }
    if (g < n) row[g] = s[tid] - v;
    if (tid == 255) bsum[blockIdx.x] = s[255];
}

// Merged scan_top + add_offsets: every block re-scans bsum (nb <= 256) in LDS.
__global__ void add_offsets(int* row, const int* bsum, int* cursor,
                            int nb, int n, int E) {
    __shared__ int sc[256];
    __shared__ int blockoff;
    int tid = threadIdx.x;
    int v = (tid < nb) ? bsum[tid] : 0;
    sc[tid] = v;
    __syncthreads();
    for (int o = 1; o < 256; o <<= 1) {
        int t = (tid >= o) ? sc[tid - o] : 0;
        __syncthreads();
        sc[tid] += t;
        __syncthreads();
    }
    if (tid == 0) blockoff = (blockIdx.x == 0) ? 0 : sc[blockIdx.x - 1];
    __syncthreads();
    int g = blockIdx.x * 256 + tid;
    if (g < n) {
        int r = row[g] + blockoff;
        row[g] = r;
        cursor[g] = r;        // cursor aliases counts (dead after scan)
        if (g == 0) row[n] = E;
    }
}

__global__ void scatter_kernel(const void* ei, const int* flags, int E,
                               int* cursor, unsigned short* csr_src, int n) {
    int e = blockIdx.x * 256 + threadIdx.x;
    if (e >= E) return;
    int is32 = flags[0] & 1;
    int s = edge_at(ei, is32, e);
    int d = edge_at(ei, is32, (long long)E + e);
    if ((unsigned)d >= (unsigned)n) return;
    if ((unsigned)s >= (unsigned)n) s = 0;
    int pos = atomicAdd(&cursor[d], 1);
    csr_src[pos] = (unsigned short)s;
}

// ---------------------------------------------------------------------------
// One wave per dst node, lane = slot(0-7)*8 + head(0-7) for the stats side,
// lane covers features [lane*4, lane*4+4) (head l3 = lane>>3) for aggregation.
// SINGLE-PASS flash-style online softmax: stats and aggregation fused; acc is
// rescaled by exp(m_old - m_new) per 8-edge chunk and normalized by 1/s at the
// end. Halves the edge-list traversals and removes the duplicate asrc gather
// + lrelu/exp of the old two-pass structure. csr + asrc prefetched one chunk
// ahead; h-row gathers issued before the softmax VALU chain to overlap.
__global__ __launch_bounds__(256) void gat_node(const _Float16* h, const _Float16* asrc,
        const _Float16* adst, const int* row, const unsigned short* csr_src,
        const void* c0, const void* c1, const void* c2,
        const int* flags, float* out, int n) {
    int fl = flags[0];
    int isf32 = fl & 2;
    const void *asu, *adu, *bias;
    resolve3(c0, c1, c2, fl, &asu, &adu, &bias);
    (void)asu; (void)adu;
    int wid  = (blockIdx.x * 256 + threadIdx.x) >> 6;
    int lane = threadIdx.x & 63;
    if (wid >= n) return;
    int beg = row[wid], end = row[wid + 1];
    int slot = lane >> 3, head = lane & 7;   // stats layout
    int l3   = lane >> 3;                    // feature lane's head

    float ad_l = (float)adst[(size_t)wid * 8 + head];

    float m = -1e30f, s = 0.f;
    float acc0 = 0.f, acc1 = 0.f, acc2 = 0.f, acc3 = 0.f;
    const _Float16* hb = h + lane * 4;

    // prefetch first chunk's csr + asrc
    int p = beg + slot;
    int act = p < end;
    int sn = act ? (int)csr_src[p] : 0;
    float av = (float)asrc[(size_t)sn * 8 + head];

    for (int p0 = beg; p0 < end; p0 += 8) {
        int actc = act, snc = sn;
        float avc = av;

        // issue this chunk's h-row gathers first (they only need snc)
        int sn_e[8];
#pragma unroll
        for (int e = 0; e < 8; ++e) sn_e[e] = __shfl(snc, e * 8, 64);
        halfx4 hv[8];
#pragma unroll
        for (int e = 0; e < 8; ++e)
            hv[e] = *(const halfx4*)(hb + (size_t)sn_e[e] * HF);

        // prefetch next chunk's csr + asrc
        int pn = p0 + 8 + slot;
        act = pn < end;
        sn = act ? (int)csr_src[pn] : 0;
        av = (float)asrc[(size_t)sn * 8 + head];

        // online softmax update (per head, shared across the 8 slots)
        float v = avc + ad_l;
        v = v > 0.f ? v : NEG_SLOPE * v;
        v = actc ? v : -1e30f;
        float vm = fmaxf(v, __shfl_xor(v, 8, 64));
        vm = fmaxf(vm, __shfl_xor(vm, 16, 64));
        vm = fmaxf(vm, __shfl_xor(vm, 32, 64));
        float mn = fmaxf(m, vm);
        float scale = __expf(m - mn);              // uniform per head
        float t = actc ? __expf(v - mn) : 0.f;     // unnormalized weight
        s = s * scale + t;
        m = mn;

        float scale_f = __shfl(scale, l3, 64);     // my feature head's scale
        acc0 *= scale_f; acc1 *= scale_f; acc2 *= scale_f; acc3 *= scale_f;
#pragma unroll
        for (int e = 0; e < 8; ++e) {
            float a_e = __shfl(t, e * 8 + l3, 64);
            acc0 += a_e * (float)hv[e][0];
            acc1 += a_e * (float)hv[e][1];
            acc2 += a_e * (float)hv[e][2];
            acc3 += a_e * (float)hv[e][3];
        }
    }

    // total s per head (sum over the 8 slots)
    s += __shfl_xor(s, 8, 64);
    s += __shfl_xor(s, 16, 64);
    s += __shfl_xor(s, 32, 64);
    float inv = s > 0.f ? 1.f / s : 0.f;
    float inv_f = __shfl(inv, l3, 64);

    int cb = lane * 4;
    floatx4 o;
    o[0] = acc0 * inv_f + fload(bias, isf32, cb);
    o[1] = acc1 * inv_f + fload(bias, isf32, cb + 1);
    o[2] = acc2 * inv_f + fload(bias, isf32, cb + 2);
    o[3] = acc3 * inv_f + fload(bias, isf32, cb + 3);
    *(floatx4*)(out + (size_t)wid * HF + cb) = o;
}

// ---------------------------------------------------------------------------
extern "C" void kernel_launch(void* const* d_in, const int* in_sizes, int n_in,
                              void* d_out, int out_size, void* d_ws, size_t ws_size,
                              hipStream_t stream) {
    // Content-based input identification (robust to any d_in permutation).
    int order[16];
    for (int i = 0; i < n_in && i < 16; ++i) order[i] = i;
    for (int i = 0; i < n_in - 1; ++i)
        for (int j = i + 1; j < n_in; ++j)
            if (in_sizes[order[j]] > in_sizes[order[i]]) {
                int t = order[i]; order[i] = order[j]; order[j] = t;
            }
    int ix  = order[0];                       // x (12.8M)
    int iei = order[1];                       // edge_index (2M)
    int iw  = order[2];                       // W (65536)
    int cand[3], nc = 0;
    for (int i = 0; i < n_in && nc < 3; ++i)
        if (i != ix && i != iei && i != iw) cand[nc++] = i;

    const void* x   = d_in[ix];
    const void* W   = d_in[iw];
    const void* ei  = d_in[iei];
    const void* ca0 = d_in[cand[0]];
    const void* ca1 = d_in[cand[1]];
    const void* ca2 = d_in[cand[2]];
    float* out = (float*)d_out;               // reference output dtype: float32

    int N = in_sizes[ix] / F_IN;    // 50000
    int E = in_sizes[iei] / 2;      // 1000000

    char* ws = (char*)d_ws;
    size_t off = 0;
    auto alloc = [&](size_t bytes) -> void* {
        void* p = ws + off;
        off += (bytes + 255) & ~(size_t)255;
        return p;
    };
    int*            flags  = (int*)alloc(16);
    int*            counts = (int*)alloc((size_t)N * 4);
    size_t          zero_span = off;          // memset [0, zero_span)
    int*            cursor = counts;
    int*            bsum   = (int*)alloc(256 * 4);
    int*            rowp   = (int*)alloc(((size_t)N + 1) * 4);
    unsigned short* Wt     = (unsigned short*)alloc(256 * 256 * 2);
    _Float16*       asrc   = (_Float16*)alloc((size_t)N * HEADS * 2);
    _Float16*       adst   = (_Float16*)alloc((size_t)N * HEADS * 2);
    unsigned short* csr    = (unsigned short*)alloc((size_t)E * 2);
    _Float16*       h      = (_Float16*)alloc((size_t)N * HF * 2);

    hipMemsetAsync(ws, 0, zero_span, stream);            // flags + counts
    hipMemsetAsync(csr, 0, (size_t)E * 2, stream);       // safety: node 0

    detect_all<<<256, 256, 0, stream>>>((const unsigned int*)ei, E,
                                        (const unsigned short*)x, in_sizes[ix], flags);
    int cap = in_sizes[ix] < (1 << 21) ? in_sizes[ix] : (1 << 21);
    int tot = (cap + 1) / 2;
    finalize_misc<<<1, 256, 0, stream>>>((const unsigned int*)ca0,
                                         (const unsigned int*)ca1,
                                         (const unsigned int*)ca2, flags, tot);
    transpose_w<<<256, 256, 0, stream>>>(W, Wt, flags);

    int rowTiles = N / 16;                               // 3125 waves
    int gemmBlocks = (rowTiles * 64 + 255) / 256;        // 782
    gemm_h<<<gemmBlocks, 256, 0, stream>>>(x, (const short*)Wt, h, flags, N);

    att_coef<<<(N * HEADS + 255) / 256, 256, 0, stream>>>(h, ca0, ca1, ca2,
                                                          asrc, adst, flags, N);

    hist_kernel<<<(E + 255) / 256, 256, 0, stream>>>(ei, flags, E, counts, N);

    int nb = (N + 255) / 256;                            // 196
    scan_blocks<<<nb, 256, 0, stream>>>(counts, rowp, bsum, N);
    add_offsets<<<nb, 256, 0, stream>>>(rowp, bsum, cursor, nb, N, E);
    scatter_kernel<<<(E + 255) / 256, 256, 0, stream>>>(ei, flags, E, cursor, csr, N);

    gat_node<<<(N + 3) / 4, 256, 0, stream>>>(h, asrc, adst, rowp, csr,
                                              ca0, ca1, ca2, flags, out, N);
}